// Round 15
// baseline (126.683 us; speedup 1.0000x reference)
//
#include <hip/hip_runtime.h>
#include <hip/hip_fp16.h>
#include <math.h>

#define BB 2
#define NN 2048
#define NP1 2049
#define DM 128
#define NH 8
#define DK 16
#define RWIN 4
#define GRID_W 64
#define QPB 2        /* queries per attn block */
#define CAND_PQ 160  /* per-query candidate cap; binom mean ~36, sd ~6 */

__device__ __forceinline__ void unpack8(uint4 r, float* f) {
    float2 t;
    t = __half22float2(*(const __half2*)&r.x); f[0] = t.x; f[1] = t.y;
    t = __half22float2(*(const __half2*)&r.y); f[2] = t.x; f[3] = t.y;
    t = __half22float2(*(const __half2*)&r.z); f[4] = t.x; f[5] = t.y;
    t = __half22float2(*(const __half2*)&r.w); f[6] = t.x; f[7] = t.y;
}

// ---------------- QKV projection (R9's kernel, unchanged: control) ----------------

#define QKV_ROWS 8

__global__ __launch_bounds__(384) void qkv_kernel(
    const float* __restrict__ z, const float* __restrict__ patch,
    const float* __restrict__ Wq, const float* __restrict__ bq,
    const float* __restrict__ Wk, const float* __restrict__ bk,
    const float* __restrict__ Wv, const float* __restrict__ bv,
    float* __restrict__ q, __half* __restrict__ k, __half* __restrict__ v) {
    __shared__ float zrow[QKV_ROWS][DM];
    const int tid = threadIdx.x;
    const int mat = tid >> 7;          // 0=q 1=k 2=v, wave-uniform
    const int rem = tid & 127;
    const int cg = rem & 31;           // cols cg*4..cg*4+3
    const int rs = rem >> 5;           // rows rs, rs+4
    const int r0 = blockIdx.x * QKV_ROWS;
    const int NROWS = BB * NP1;

    if (tid < QKV_ROWS * DM / 4) {
        int r = tid >> 5, q4 = tid & 31;
        int row = r0 + r;
        float4 val = make_float4(0.f, 0.f, 0.f, 0.f);
        if (row < NROWS) {
            int b = row / NP1, ti = row % NP1;
            const float* src = (ti < NN) ? (z + ((size_t)b * NN + ti) * DM)
                                         : (patch + (size_t)b * DM);
            val = ((const float4*)src)[q4];
        }
        *((float4*)&zrow[r][q4 * 4]) = val;
    }
    __syncthreads();

    const float* W    = (mat == 0) ? Wq : (mat == 1) ? Wk : Wv;
    const float* bias = (mat == 0) ? bq : (mat == 1) ? bk : bv;

    float a0x = 0.f, a0y = 0.f, a0z = 0.f, a0w = 0.f;
    float a1x = 0.f, a1y = 0.f, a1z = 0.f, a1w = 0.f;
#pragma unroll 8
    for (int kk = 0; kk < DM; ++kk) {
        float4 w4 = *((const float4*)(W + kk * DM + cg * 4));
        float z0 = zrow[rs][kk];
        float z1 = zrow[rs + 4][kk];
        a0x = fmaf(z0, w4.x, a0x); a0y = fmaf(z0, w4.y, a0y);
        a0z = fmaf(z0, w4.z, a0z); a0w = fmaf(z0, w4.w, a0w);
        a1x = fmaf(z1, w4.x, a1x); a1y = fmaf(z1, w4.y, a1y);
        a1z = fmaf(z1, w4.z, a1z); a1w = fmaf(z1, w4.w, a1w);
    }
    float4 b4 = *((const float4*)(bias + cg * 4));
    float4 o0 = make_float4(a0x + b4.x, a0y + b4.y, a0z + b4.z, a0w + b4.w);
    float4 o1 = make_float4(a1x + b4.x, a1y + b4.y, a1z + b4.z, a1w + b4.w);

#pragma unroll
    for (int rr = 0; rr < 2; ++rr) {
        int row = r0 + rs + rr * 4;
        if (row >= NROWS) break;
        float4 val = rr ? o1 : o0;
        int b = row / NP1, ti = row % NP1;
        if (mat == 0) {
            if (ti < NN) ((float4*)(q + ((size_t)b * NN + ti) * DM))[cg] = val;
        } else {
            __half2 p0 = __floats2half2_rn(val.x, val.y);
            __half2 p1 = __floats2half2_rn(val.z, val.w);
            uint2 st;
            st.x = *(unsigned int*)&p0;
            st.y = *(unsigned int*)&p1;
            __half* dst = ((mat == 1) ? k : v) + ((size_t)b * NP1 + ti) * DM;
            ((uint2*)dst)[cg] = st;
        }
    }
}

// ---------------- fused: 2-query scan + sparse attention + out-proj ----------------
// Max-TLP variant: grid 2048 blocks (32 waves/CU cap), 256 threads =
// 2 queries x 8 heads x 16 key-slots -> keys/thread ~2.3. fp16 K/V uint4
// gathers. Out-projection: one column per thread (coalesced scalar Wo
// loads, L2-hot). No-max softmax (logits O(0.3), exp-safe). Dead queries:
// scan skips (M=0), patch keeps l>0, output gated to 0.

__global__ __launch_bounds__(256) void attn_out_kernel(
    const float* __restrict__ q, const __half* __restrict__ k, const __half* __restrict__ v,
    const int* __restrict__ positions, const float* __restrict__ alive,
    const float* __restrict__ rel_bias, const float* __restrict__ Wo,
    const float* __restrict__ bo, float* __restrict__ out) {
    const int tid = threadIdx.x;
    const int qq = tid >> 7;          // 0..1 query in group
    const int l7 = tid & 127;
    const int h = l7 >> 4;            // 0..7 head
    const int s = l7 & 15;            // 0..15 key slot
    const int r0 = blockIdx.x * QPB;  // global query base (same batch: NN%QPB==0)
    const int b = r0 >> 11;
    const int bi = r0 + qq;

    __shared__ float sbias[NH * 81];
    __shared__ int   spx[QPB], spy[QPB];
    __shared__ float sal[QPB];
    __shared__ int   mcount[QPB];
    __shared__ int   cand[QPB][CAND_PQ];
    __shared__ float po[QPB * 16][DM + 1];
    __shared__ float pl[QPB * 16][NH + 1];
    __shared__ float srow[QPB][DM + 1];

    if (tid < QPB) {
        mcount[tid] = 0;
        int gbi = r0 + tid;
        spx[tid] = positions[gbi * 2 + 0];
        spy[tid] = positions[gbi * 2 + 1];
        sal[tid] = alive[gbi];
    }
    for (int t = tid; t < NH * 81; t += 256) sbias[t] = rel_bias[t];

    const __half* kb = k + (size_t)b * NP1 * DM;
    const __half* vb = v + (size_t)b * NP1 * DM;

    // q segment for (query qq, head h), pre-scaled by 1/sqrt(dk)
    float qf[16];
    {
        const float4* qr = (const float4*)(q + (size_t)bi * DM + h * DK);
#pragma unroll
        for (int e = 0; e < 4; ++e) {
            float4 t4 = qr[e];
            qf[e * 4 + 0] = t4.x * 0.25f; qf[e * 4 + 1] = t4.y * 0.25f;
            qf[e * 4 + 2] = t4.z * 0.25f; qf[e * 4 + 3] = t4.w * 0.25f;
        }
    }

    __syncthreads(); // spos/sal/mcount/sbias visible

    int qx[QPB], qy[QPB], qi[QPB];
    float qa[QPB];
#pragma unroll
    for (int u = 0; u < QPB; ++u) {
        qx[u] = spx[u]; qy[u] = spy[u]; qa[u] = sal[u];
        qi[u] = (r0 + u) & (NN - 1);
    }

    // one scan over all agents, 2 query tests each
    {
        const int2* pb = (const int2*)(positions + (size_t)b * NN * 2);
        const float* ab = alive + (size_t)b * NN;
#pragma unroll
        for (int u = 0; u < NN / 256; ++u) {
            int j = u * 256 + tid;
            int2 pj = pb[j];
            float aj = ab[j];
            if (aj > 0.5f) {
                int packed = j | (pj.x << 16) | (pj.y << 24);
#pragma unroll
                for (int qn = 0; qn < QPB; ++qn) {
                    int dx = pj.x - qx[qn]; dx = dx < 0 ? -dx : dx;
                    int dy = pj.y - qy[qn]; dy = dy < 0 ? -dy : dy;
                    int ch = dx > dy ? dx : dy;
                    if (ch <= RWIN && j != qi[qn] && qa[qn] > 0.5f) {
                        int slot = atomicAdd(&mcount[qn], 1);
                        if (slot < CAND_PQ) cand[qn][slot] = packed;
                    }
                }
            }
        }
    }
    __syncthreads();
    int M = mcount[qq]; if (M > CAND_PQ) M = CAND_PQ;
    const int pix = qx[qq], piy = qy[qq];

    float l = 0.f;
    float o[16];
#pragma unroll
    for (int e = 0; e < 16; ++e) o[e] = 0.f;

    if (s == 0) { // patch column: always allowed, no bias; keeps l>0 for dead queries
        const uint4* kr = (const uint4*)(kb + (size_t)NN * DM + h * DK);
        uint4 ka = kr[0], kb4 = kr[1];
        const uint4* vr = (const uint4*)(vb + (size_t)NN * DM + h * DK);
        uint4 va = vr[0], vb4 = vr[1];
        float kf[16], vf[16];
        unpack8(ka, kf); unpack8(kb4, kf + 8);
        unpack8(va, vf); unpack8(vb4, vf + 8);
        float d = 0.f;
#pragma unroll
        for (int e = 0; e < 16; ++e) d = fmaf(qf[e], kf[e], d);
        float p = __expf(d);
        l += p;
#pragma unroll
        for (int e = 0; e < 16; ++e) o[e] = fmaf(p, vf[e], o[e]);
    }

    for (int t = s; t < M; t += 16) {
        int packed = cand[qq][t];
        int j = packed & 0xFFFF;
        const uint4* kr = (const uint4*)(kb + (size_t)j * DM + h * DK);
        uint4 ka = kr[0], kb4 = kr[1];
        const uint4* vr = (const uint4*)(vb + (size_t)j * DM + h * DK);
        uint4 va = vr[0], vb4 = vr[1];
        float kf[16], vf[16];
        unpack8(ka, kf); unpack8(kb4, kf + 8);
        unpack8(va, vf); unpack8(vb4, vf + 8);
        float d = 0.f;
#pragma unroll
        for (int e = 0; e < 16; ++e) d = fmaf(qf[e], kf[e], d);
        int pjx = (packed >> 16) & 0xFF;
        int pjy = (packed >> 24) & 0xFF;
        float bias = sbias[h * 81 + (pjx - pix + RWIN) * 9 + (pjy - piy + RWIN)];
        float p = __expf(d + bias);
        l += p;
#pragma unroll
        for (int e = 0; e < 16; ++e) o[e] = fmaf(p, vf[e], o[e]);
    }

    // reduction over the 16 key-slots via LDS
    {
        const int prow = qq * 16 + s;
#pragma unroll
        for (int e = 0; e < 16; ++e) po[prow][h * DK + e] = o[e];
        pl[prow][h] = l;
    }
    __syncthreads();
    {
        const int c = tid & 127;
        const int g = tid >> 7; // query g
        const int ch = c >> 4;
        float acc = 0.f, lh = 0.f;
#pragma unroll
        for (int ss = 0; ss < 16; ++ss) {
            acc += po[g * 16 + ss][c];
            lh  += pl[g * 16 + ss][ch];
        }
        srow[g][c] = acc / lh;
    }
    __syncthreads();

    // output projection: one column per thread (coalesced scalar Wo loads)
    {
        const int oq = tid >> 7;
        const int col = tid & 127;
        float acc = 0.f;
#pragma unroll 8
        for (int kk = 0; kk < DM; ++kk)
            acc = fmaf(srow[oq][kk], Wo[kk * DM + col], acc);
        float ga = sal[oq] > 0.5f ? 1.f : 0.f;
        out[(size_t)(r0 + oq) * DM + col] = (acc + bo[col]) * ga;
    }
}

extern "C" void kernel_launch(void* const* d_in, const int* in_sizes, int n_in,
                              void* d_out, int out_size, void* d_ws, size_t ws_size,
                              hipStream_t stream) {
    const float* z         = (const float*)d_in[0];
    const float* patch     = (const float*)d_in[1];
    const int*   positions = (const int*)d_in[2];
    const float* alive     = (const float*)d_in[3];
    const float* Wq        = (const float*)d_in[4];
    const float* bq        = (const float*)d_in[5];
    const float* Wk        = (const float*)d_in[6];
    const float* bk        = (const float*)d_in[7];
    const float* Wv        = (const float*)d_in[8];
    const float* bv        = (const float*)d_in[9];
    const float* Wo        = (const float*)d_in[10];
    const float* bo        = (const float*)d_in[11];
    const float* rel_bias  = (const float*)d_in[12];
    float* out = (float*)d_out;

    char* ws = (char*)d_ws;
    size_t off = 0;
    auto alloc = [&](size_t bytes) -> void* {
        void* p = ws + off;
        off += (bytes + 255) & ~(size_t)255;
        return p;
    };
    float*  q = (float*)alloc((size_t)BB * NN * DM * 4);
    __half* k = (__half*)alloc((size_t)BB * NP1 * DM * 2);
    __half* v = (__half*)alloc((size_t)BB * NP1 * DM * 2);

    qkv_kernel<<<(BB * NP1 + QKV_ROWS - 1) / QKV_ROWS, 384, 0, stream>>>(z, patch, Wq, bq, Wk, bk, Wv, bv, q, k, v);
    attn_out_kernel<<<(BB * NN) / QPB, 256, 0, stream>>>(q, k, v, positions, alive, rel_bias, Wo, bo, out);
}

// Round 16
// 122.980 us; speedup vs baseline: 1.0301x; 1.0301x over previous
//
#include <hip/hip_runtime.h>
#include <hip/hip_fp16.h>
#include <math.h>

#define BB 2
#define NN 2048
#define NP1 2049
#define DM 128
#define NH 8
#define DK 16
#define RWIN 4
#define GRID_W 64
#define QPB 4        /* queries per attn block: R13-verified optimum (8->4 +3.5us, 4->2 -4.1us) */
#define CAND_PQ 160  /* per-query candidate cap; binom mean ~36, sd ~6 */

__device__ __forceinline__ void unpack8(uint4 r, float* f) {
    float2 t;
    t = __half22float2(*(const __half2*)&r.x); f[0] = t.x; f[1] = t.y;
    t = __half22float2(*(const __half2*)&r.y); f[2] = t.x; f[3] = t.y;
    t = __half22float2(*(const __half2*)&r.z); f[4] = t.x; f[5] = t.y;
    t = __half22float2(*(const __half2*)&r.w); f[6] = t.x; f[7] = t.y;
}

// ---------------- QKV projection ----------------
// 384 threads = 3 mats x (32 col-groups x 4 row-slots). Thread owns 4
// consecutive output columns (float4 W loads) and rows rs, rs+4.
// K/V stored fp16 (halves the gathered working set); q stays fp32.

#define QKV_ROWS 8

__global__ __launch_bounds__(384) void qkv_kernel(
    const float* __restrict__ z, const float* __restrict__ patch,
    const float* __restrict__ Wq, const float* __restrict__ bq,
    const float* __restrict__ Wk, const float* __restrict__ bk,
    const float* __restrict__ Wv, const float* __restrict__ bv,
    float* __restrict__ q, __half* __restrict__ k, __half* __restrict__ v) {
    __shared__ float zrow[QKV_ROWS][DM];
    const int tid = threadIdx.x;
    const int mat = tid >> 7;          // 0=q 1=k 2=v, wave-uniform
    const int rem = tid & 127;
    const int cg = rem & 31;           // cols cg*4..cg*4+3
    const int rs = rem >> 5;           // rows rs, rs+4
    const int r0 = blockIdx.x * QKV_ROWS;
    const int NROWS = BB * NP1;

    if (tid < QKV_ROWS * DM / 4) {
        int r = tid >> 5, q4 = tid & 31;
        int row = r0 + r;
        float4 val = make_float4(0.f, 0.f, 0.f, 0.f);
        if (row < NROWS) {
            int b = row / NP1, ti = row % NP1;
            const float* src = (ti < NN) ? (z + ((size_t)b * NN + ti) * DM)
                                         : (patch + (size_t)b * DM);
            val = ((const float4*)src)[q4];
        }
        *((float4*)&zrow[r][q4 * 4]) = val;
    }
    __syncthreads();

    const float* W    = (mat == 0) ? Wq : (mat == 1) ? Wk : Wv;
    const float* bias = (mat == 0) ? bq : (mat == 1) ? bk : bv;

    float a0x = 0.f, a0y = 0.f, a0z = 0.f, a0w = 0.f;
    float a1x = 0.f, a1y = 0.f, a1z = 0.f, a1w = 0.f;
#pragma unroll 8
    for (int kk = 0; kk < DM; ++kk) {
        float4 w4 = *((const float4*)(W + kk * DM + cg * 4));
        float z0 = zrow[rs][kk];
        float z1 = zrow[rs + 4][kk];
        a0x = fmaf(z0, w4.x, a0x); a0y = fmaf(z0, w4.y, a0y);
        a0z = fmaf(z0, w4.z, a0z); a0w = fmaf(z0, w4.w, a0w);
        a1x = fmaf(z1, w4.x, a1x); a1y = fmaf(z1, w4.y, a1y);
        a1z = fmaf(z1, w4.z, a1z); a1w = fmaf(z1, w4.w, a1w);
    }
    float4 b4 = *((const float4*)(bias + cg * 4));
    float4 o0 = make_float4(a0x + b4.x, a0y + b4.y, a0z + b4.z, a0w + b4.w);
    float4 o1 = make_float4(a1x + b4.x, a1y + b4.y, a1z + b4.z, a1w + b4.w);

#pragma unroll
    for (int rr = 0; rr < 2; ++rr) {
        int row = r0 + rs + rr * 4;
        if (row >= NROWS) break;
        float4 val = rr ? o1 : o0;
        int b = row / NP1, ti = row % NP1;
        if (mat == 0) {
            if (ti < NN) ((float4*)(q + ((size_t)b * NN + ti) * DM))[cg] = val;
        } else {
            __half2 p0 = __floats2half2_rn(val.x, val.y);
            __half2 p1 = __floats2half2_rn(val.z, val.w);
            uint2 st;
            st.x = *(unsigned int*)&p0;
            st.y = *(unsigned int*)&p1;
            __half* dst = ((mat == 1) ? k : v) + ((size_t)b * NP1 + ti) * DM;
            ((uint2*)dst)[cg] = st;
        }
    }
}

// ---------------- fused: 4-query scan + sparse attention + out-proj ----------------
// R13 optimum: grid 1024 blocks (16 waves/CU), 256 threads =
// 4 queries x 8 heads x 8 key-slots -> keys/thread ~4.6. fp16 K/V uint4
// gathers. Out-projection: one wave per query, kk split across lane halves,
// combined via shfl_xor(32) to keep float4 Wo loads. No-max softmax (logits
// O(0.3), exp-safe). Dead queries: scan skips (M=0), patch keeps l>0,
// output gated to 0.

__global__ __launch_bounds__(256) void attn_out_kernel(
    const float* __restrict__ q, const __half* __restrict__ k, const __half* __restrict__ v,
    const int* __restrict__ positions, const float* __restrict__ alive,
    const float* __restrict__ rel_bias, const float* __restrict__ Wo,
    const float* __restrict__ bo, float* __restrict__ out) {
    const int tid = threadIdx.x;
    const int qq = tid >> 6;          // 0..3 query in group
    const int l6 = tid & 63;
    const int h = l6 >> 3;            // 0..7 head
    const int s = l6 & 7;             // 0..7 key slot
    const int r0 = blockIdx.x * QPB;  // global query base (same batch: NN%QPB==0)
    const int b = r0 >> 11;
    const int bi = r0 + qq;

    __shared__ float sbias[NH * 81];
    __shared__ int   spx[QPB], spy[QPB];
    __shared__ float sal[QPB];
    __shared__ int   mcount[QPB];
    __shared__ int   cand[QPB][CAND_PQ];
    __shared__ float po[QPB * 8][DM + 1];
    __shared__ float pl[QPB * 8][NH + 1];
    __shared__ float srow[QPB][DM + 1];

    if (tid < QPB) {
        mcount[tid] = 0;
        int gbi = r0 + tid;
        spx[tid] = positions[gbi * 2 + 0];
        spy[tid] = positions[gbi * 2 + 1];
        sal[tid] = alive[gbi];
    }
    for (int t = tid; t < NH * 81; t += 256) sbias[t] = rel_bias[t];

    const __half* kb = k + (size_t)b * NP1 * DM;
    const __half* vb = v + (size_t)b * NP1 * DM;

    // q segment for (query qq, head h), pre-scaled by 1/sqrt(dk)
    float qf[16];
    {
        const float4* qr = (const float4*)(q + (size_t)bi * DM + h * DK);
#pragma unroll
        for (int e = 0; e < 4; ++e) {
            float4 t4 = qr[e];
            qf[e * 4 + 0] = t4.x * 0.25f; qf[e * 4 + 1] = t4.y * 0.25f;
            qf[e * 4 + 2] = t4.z * 0.25f; qf[e * 4 + 3] = t4.w * 0.25f;
        }
    }

    __syncthreads(); // spos/sal/mcount/sbias visible

    int qx[QPB], qy[QPB], qi[QPB];
    float qa[QPB];
#pragma unroll
    for (int u = 0; u < QPB; ++u) {
        qx[u] = spx[u]; qy[u] = spy[u]; qa[u] = sal[u];
        qi[u] = (r0 + u) & (NN - 1);
    }

    // one scan over all agents, 4 query tests each
    {
        const int2* pb = (const int2*)(positions + (size_t)b * NN * 2);
        const float* ab = alive + (size_t)b * NN;
#pragma unroll
        for (int u = 0; u < NN / 256; ++u) {
            int j = u * 256 + tid;
            int2 pj = pb[j];
            float aj = ab[j];
            if (aj > 0.5f) {
                int packed = j | (pj.x << 16) | (pj.y << 24);
#pragma unroll
                for (int qn = 0; qn < QPB; ++qn) {
                    int dx = pj.x - qx[qn]; dx = dx < 0 ? -dx : dx;
                    int dy = pj.y - qy[qn]; dy = dy < 0 ? -dy : dy;
                    int ch = dx > dy ? dx : dy;
                    if (ch <= RWIN && j != qi[qn] && qa[qn] > 0.5f) {
                        int slot = atomicAdd(&mcount[qn], 1);
                        if (slot < CAND_PQ) cand[qn][slot] = packed;
                    }
                }
            }
        }
    }
    __syncthreads();
    int M = mcount[qq]; if (M > CAND_PQ) M = CAND_PQ;
    const int pix = qx[qq], piy = qy[qq];

    float l = 0.f;
    float o[16];
#pragma unroll
    for (int e = 0; e < 16; ++e) o[e] = 0.f;

    if (s == 0) { // patch column: always allowed, no bias; keeps l>0 for dead queries
        const uint4* kr = (const uint4*)(kb + (size_t)NN * DM + h * DK);
        uint4 ka = kr[0], kb4 = kr[1];
        const uint4* vr = (const uint4*)(vb + (size_t)NN * DM + h * DK);
        uint4 va = vr[0], vb4 = vr[1];
        float kf[16], vf[16];
        unpack8(ka, kf); unpack8(kb4, kf + 8);
        unpack8(va, vf); unpack8(vb4, vf + 8);
        float d = 0.f;
#pragma unroll
        for (int e = 0; e < 16; ++e) d = fmaf(qf[e], kf[e], d);
        float p = __expf(d);
        l += p;
#pragma unroll
        for (int e = 0; e < 16; ++e) o[e] = fmaf(p, vf[e], o[e]);
    }

    for (int t = s; t < M; t += 8) {
        int packed = cand[qq][t];
        int j = packed & 0xFFFF;
        const uint4* kr = (const uint4*)(kb + (size_t)j * DM + h * DK);
        uint4 ka = kr[0], kb4 = kr[1];
        const uint4* vr = (const uint4*)(vb + (size_t)j * DM + h * DK);
        uint4 va = vr[0], vb4 = vr[1];
        float kf[16], vf[16];
        unpack8(ka, kf); unpack8(kb4, kf + 8);
        unpack8(va, vf); unpack8(vb4, vf + 8);
        float d = 0.f;
#pragma unroll
        for (int e = 0; e < 16; ++e) d = fmaf(qf[e], kf[e], d);
        int pjx = (packed >> 16) & 0xFF;
        int pjy = (packed >> 24) & 0xFF;
        float bias = sbias[h * 81 + (pjx - pix + RWIN) * 9 + (pjy - piy + RWIN)];
        float p = __expf(d + bias);
        l += p;
#pragma unroll
        for (int e = 0; e < 16; ++e) o[e] = fmaf(p, vf[e], o[e]);
    }

    // reduction over the 8 key-slots via LDS
    {
        const int prow = qq * 8 + s;
#pragma unroll
        for (int e = 0; e < 16; ++e) po[prow][h * DK + e] = o[e];
        pl[prow][h] = l;
    }
    __syncthreads();
    {
        const int c = tid & 127;
        const int g = tid >> 7; // 0/1 -> queries g*2..g*2+1
        const int ch = c >> 4;
#pragma unroll
        for (int qn = 0; qn < 2; ++qn) {
            int qq2 = g * 2 + qn;
            float acc = 0.f, lh = 0.f;
#pragma unroll
            for (int ss = 0; ss < 8; ++ss) {
                acc += po[qq2 * 8 + ss][c];
                lh  += pl[qq2 * 8 + ss][ch];
            }
            srow[qq2][c] = acc / lh;
        }
    }
    __syncthreads();

    // output projection: wave w handles query w; lanes split kk in halves
    // (half = l6>>5, m = l6&31 -> cols m*4..m*4+3), combine via shfl_xor(32).
    {
        const int oq = qq;
        const int half = l6 >> 5;
        const int m = l6 & 31;
        const float* Wb = Wo + (size_t)half * 64 * DM + m * 4;
        const float* sr = &srow[oq][half * 64];
        float ax = 0.f, ay = 0.f, az = 0.f, aw = 0.f;
#pragma unroll 16
        for (int kk = 0; kk < 64; ++kk) {
            float sv = sr[kk];
            float4 w4 = *((const float4*)(Wb + (size_t)kk * DM));
            ax = fmaf(sv, w4.x, ax); ay = fmaf(sv, w4.y, ay);
            az = fmaf(sv, w4.z, az); aw = fmaf(sv, w4.w, aw);
        }
        ax += __shfl_xor(ax, 32, 64); ay += __shfl_xor(ay, 32, 64);
        az += __shfl_xor(az, 32, 64); aw += __shfl_xor(aw, 32, 64);
        if (half == 0) {
            float ga = sal[oq] > 0.5f ? 1.f : 0.f;
            float4 b4 = *((const float4*)(bo + m * 4));
            float4 r;
            r.x = (ax + b4.x) * ga; r.y = (ay + b4.y) * ga;
            r.z = (az + b4.z) * ga; r.w = (aw + b4.w) * ga;
            ((float4*)(out + (size_t)(r0 + oq) * DM))[m] = r;
        }
    }
}

extern "C" void kernel_launch(void* const* d_in, const int* in_sizes, int n_in,
                              void* d_out, int out_size, void* d_ws, size_t ws_size,
                              hipStream_t stream) {
    const float* z         = (const float*)d_in[0];
    const float* patch     = (const float*)d_in[1];
    const int*   positions = (const int*)d_in[2];
    const float* alive     = (const float*)d_in[3];
    const float* Wq        = (const float*)d_in[4];
    const float* bq        = (const float*)d_in[5];
    const float* Wk        = (const float*)d_in[6];
    const float* bk        = (const float*)d_in[7];
    const float* Wv        = (const float*)d_in[8];
    const float* bv        = (const float*)d_in[9];
    const float* Wo        = (const float*)d_in[10];
    const float* bo        = (const float*)d_in[11];
    const float* rel_bias  = (const float*)d_in[12];
    float* out = (float*)d_out;

    char* ws = (char*)d_ws;
    size_t off = 0;
    auto alloc = [&](size_t bytes) -> void* {
        void* p = ws + off;
        off += (bytes + 255) & ~(size_t)255;
        return p;
    };
    float*  q = (float*)alloc((size_t)BB * NN * DM * 4);
    __half* k = (__half*)alloc((size_t)BB * NP1 * DM * 2);
    __half* v = (__half*)alloc((size_t)BB * NP1 * DM * 2);

    qkv_kernel<<<(BB * NP1 + QKV_ROWS - 1) / QKV_ROWS, 384, 0, stream>>>(z, patch, Wq, bq, Wk, bk, Wv, bv, q, k, v);
    attn_out_kernel<<<(BB * NN) / QPB, 256, 0, stream>>>(q, k, v, positions, alive, rel_bias, Wo, bo, out);
}